// Round 9
// baseline (365.813 us; speedup 1.0000x reference)
//
#include <hip/hip_runtime.h>
#include <math.h>

#define FEAT_DIM 256
#define NCLS 21
#define TEMP 0.1f
#define CPX 128                 // pixels per chunk
#define RS 130                  // tile row stride in bf16 slots (260 B: 2-way banks)
#define NREP 8                  // gsum replicas

typedef float f32x4 __attribute__((ext_vector_type(4)));

__device__ __forceinline__ unsigned int cvt_pk_bf16(float lo, float hi) {
    unsigned int r;
    asm volatile("v_cvt_pk_bf16_f32 %0, %1, %2" : "=v"(r) : "v"(lo), "v"(hi));
    return r;
}

// ---------------------------------------------------------------------------
// Producer/consumer fused kernel. 1 block/CU, 8 waves.
//   waves 4-7 (producers): stream 256 chan-rows x 128 px f32 from HBM
//     (512B segments, 2 rows per dwordx4 instr), ssq partials in regs,
//     cvt_pk->bf16, stage into chunk buffer; waves 4,5 ballot-sort the two
//     64-px groups. Producers stream continuously: their only waits are the
//     two RAW barriers per chunk (lgkm-only fences; vmcnt never drained by
//     a barrier since __syncthreads is avoided in the loop).
//   waves 0-3 (consumers): 256 threads = 1 channel each; walk the 128
//     rank-sorted pixels via ds_read_u16 (2-way banks), fma with f32 iv
//     (pre-gathered by rank), flush on wave-uniform class change into a
//     thread-private s_acc cell (plain LDS RMW -- zero atomics).
// Chunk double-buffer (bf16) makes stage(t+1) overlap accumulate(t).
// ---------------------------------------------------------------------------
__global__ __launch_bounds__(512, 1)
void k_fused(const float* __restrict__ feat, const int* __restrict__ lab,
             float* __restrict__ gsum, float* __restrict__ gcnt, int N) {
    __shared__ unsigned short s_tile[2][256 * RS];          // 133120 B
    __shared__ float s_ssp[2][4][CPX];                      // 4096 B
    __shared__ float s_ivk[CPX];                            // 512 B  (iv by rank)
    __shared__ alignas(16) unsigned char s_prm[2][CPX];     // 256 B  (px by rank)
    __shared__ alignas(16) unsigned char s_scb[2][CPX];     // 256 B  (cls by rank)
    __shared__ float s_acc[NCLS * FEAT_DIM];                // 21504 B

    const int tid = threadIdx.x, lane = tid & 63, w = tid >> 6;
    const bool consumer = (w < 4);

    for (int i = tid; i < NCLS * FEAT_DIM; i += 512) s_acc[i] = 0.f;
    __syncthreads();

    const int per = (N / CPX) / gridDim.x;                  // 18
    const size_t px0 = (size_t)blockIdx.x * (size_t)per * CPX;

    float cntacc = 0.f;

    // ---- producer: stage chunk cc into buffer b --------------------------
    auto stage = [&](int cc, int b) {
        const int pw = w - 4;                // 0..3
        const int half = lane >> 5;          // row parity within pair
        const int pq = lane & 31;            // px-quad index
        const size_t po = px0 + (size_t)cc * CPX;
        const int rbase = pw * 64 + half;
        const float* fp = feat + (size_t)rbase * N + po + 4 * pq;
        unsigned short* tp0 = &s_tile[b][rbase * RS + 4 * pq];

        f32x4 ssq = {0.f, 0.f, 0.f, 0.f};
        #pragma unroll 8
        for (int i = 0; i < 32; ++i) {       // 32 row-pairs -> 64 rows/wave
            const float4 v = *reinterpret_cast<const float4*>(fp + (size_t)(2 * i) * N);
            ssq[0] = fmaf(v.x, v.x, ssq[0]);
            ssq[1] = fmaf(v.y, v.y, ssq[1]);
            ssq[2] = fmaf(v.z, v.z, ssq[2]);
            ssq[3] = fmaf(v.w, v.w, ssq[3]);
            unsigned int* tp = reinterpret_cast<unsigned int*>(tp0 + (size_t)(2 * i) * RS);
            tp[0] = cvt_pk_bf16(v.x, v.y);   // two b32 writes (4B-aligned)
            tp[1] = cvt_pk_bf16(v.z, v.w);
        }
        #pragma unroll
        for (int e = 0; e < 4; ++e) ssq[e] += __shfl_xor(ssq[e], 32);
        if (half == 0)
            *reinterpret_cast<f32x4*>(&s_ssp[b][pw][4 * pq]) = ssq;

        if (pw < 2) {                        // waves 4,5 sort groups 0,1
            const int myl = lab[po + pw * 64 + lane];
            int myrank = 0, base = 0;
            #pragma unroll 1
            for (int c = 0; c < NCLS; ++c) {
                const unsigned long long m = __ballot(myl == c);
                const int cnt = (int)__popcll(m);
                if (myl == c)
                    myrank = base + (int)__popcll(m & ((1ull << lane) - 1ull));
                if (lane == c) cntacc += (float)cnt;
                base += cnt;
            }
            s_prm[b][pw * 64 + myrank] = (unsigned char)(pw * 64 + lane);
            s_scb[b][pw * 64 + myrank] = (unsigned char)myl;
        }
    };

    // ---- consumer: accumulate chunk from buffer b ------------------------
    auto accumulate = [&](int b) {
        const int chan = tid;                // 0..255
        const unsigned short* trow = &s_tile[b][chan * RS];
        const uint4* pmv = reinterpret_cast<const uint4*>(s_prm[b]);
        const uint4* scv = reinterpret_cast<const uint4*>(s_scb[b]);

        float acc = 0.f;
        int ccur = __builtin_amdgcn_readfirstlane((int)s_scb[b][0]);

        #pragma unroll 1
        for (int bb = 0; bb < 8; ++bb) {     // 8 batches x 16 ranks
            const uint4 pm = pmv[bb];
            const uint4 sc = scv[bb];
            const unsigned int pmw[4] = {pm.x, pm.y, pm.z, pm.w};
            const unsigned int scw[4] = {sc.x, sc.y, sc.z, sc.w};
            const f32x4 vv0 = *reinterpret_cast<const f32x4*>(&s_ivk[16 * bb + 0]);
            const f32x4 vv1 = *reinterpret_cast<const f32x4*>(&s_ivk[16 * bb + 4]);
            const f32x4 vv2 = *reinterpret_cast<const f32x4*>(&s_ivk[16 * bb + 8]);
            const f32x4 vv3 = *reinterpret_cast<const f32x4*>(&s_ivk[16 * bb + 12]);

            unsigned short hv[16];
            #pragma unroll
            for (int k = 0; k < 16; ++k) {
                const int px = (int)((pmw[k >> 2] >> (8 * (k & 3))) & 255u);
                hv[k] = trow[px];            // independent, batched by compiler
            }
            #pragma unroll
            for (int k = 0; k < 16; ++k) {
                const int ck = __builtin_amdgcn_readfirstlane(
                    (int)((scw[k >> 2] >> (8 * (k & 3))) & 255u));
                if (ck != ccur) {            // wave-uniform scalar branch
                    s_acc[ccur * FEAT_DIM + chan] += acc;   // private cell
                    acc = 0.f; ccur = ck;
                }
                const float val = __builtin_bit_cast(
                    float, (unsigned int)hv[k] << 16);
                const float iv = (k < 4) ? vv0[k & 3] :
                                 (k < 8) ? vv1[k & 3] :
                                 (k < 12) ? vv2[k & 3] : vv3[k & 3];
                acc = fmaf(val, iv, acc);
            }
        }
        s_acc[ccur * FEAT_DIM + chan] += acc;
    };

    // ---- pipeline --------------------------------------------------------
    if (!consumer) stage(0, 0);
    asm volatile("s_waitcnt lgkmcnt(0)" ::: "memory");
    __builtin_amdgcn_s_barrier();                          // b1(0)

    for (int cc = 0; cc < per; ++cc) {
        const int b = cc & 1;
        if (consumer && tid < CPX) {                       // iv by rank (f32)
            const int px = (int)s_prm[b][tid];
            const float ss = s_ssp[b][0][px] + s_ssp[b][1][px] +
                             s_ssp[b][2][px] + s_ssp[b][3][px];
            s_ivk[tid] = 1.0f / fmaxf(sqrtf(ss), 1e-12f);
        }
        asm volatile("s_waitcnt lgkmcnt(0)" ::: "memory");
        __builtin_amdgcn_s_barrier();                      // b2

        if (consumer) {
            accumulate(b);
        } else if (cc + 1 < per) {
            stage(cc + 1, b ^ 1);                          // overlaps accumulate
        }
        asm volatile("s_waitcnt lgkmcnt(0)" ::: "memory");
        __builtin_amdgcn_s_barrier();                      // b1(cc+1)
    }

    __syncthreads();
    // merge: one atomic per cell into 1-of-8 replicas, block-staggered
    {
        float* grep = gsum + (size_t)(blockIdx.x & (NREP - 1)) * (NCLS * FEAT_DIM);
        const int total = NCLS * FEAT_DIM;
        const int off = (blockIdx.x * 37) % total;
        for (int k = tid; k < total; k += 512) {
            int i = k + off; if (i >= total) i -= total;
            const float v = s_acc[i];
            if (v != 0.f) atomicAdd(&grep[i], v);
        }
    }
    if ((w == 4 || w == 5) && lane < NCLS) atomicAdd(&gcnt[lane], cntacc);
}

// ---------------------------------------------------------------------------
// Finalize: sum replicas -> means -> 21x21 logits -> masked loss.
// ---------------------------------------------------------------------------
__global__ void k_final(const float* __restrict__ gsum,
                        const float* __restrict__ gcnt,
                        const float* __restrict__ proto,
                        float* __restrict__ out) {
    __shared__ float s_mean[NCLS * 257];
    __shared__ float s_icnt[NCLS];
    __shared__ float s_log[NCLS * NCLS];
    __shared__ float s_term[NCLS];

    if (threadIdx.x < NCLS)
        s_icnt[threadIdx.x] = 1.0f / fmaxf(gcnt[threadIdx.x], 1.0f);
    __syncthreads();

    for (int i = threadIdx.x; i < NCLS * FEAT_DIM; i += blockDim.x) {
        float v = 0.f;
        #pragma unroll
        for (int r = 0; r < NREP; ++r) v += gsum[r * NCLS * FEAT_DIM + i];
        const int c = i / FEAT_DIM, d = i - c * FEAT_DIM;
        s_mean[c * 257 + d] = v * s_icnt[c];
    }
    __syncthreads();

    for (int p = threadIdx.x; p < NCLS * NCLS; p += blockDim.x) {
        const int c = p / NCLS, j = p - c * NCLS;
        float acc = 0.f;
        #pragma unroll 8
        for (int d = 0; d < FEAT_DIM; ++d)
            acc += s_mean[c * 257 + d] * proto[j * FEAT_DIM + d];
        s_log[p] = acc / TEMP;
    }
    __syncthreads();

    if (threadIdx.x >= 1 && threadIdx.x < NCLS) {
        const int c = threadIdx.x;
        float m = -INFINITY;
        for (int j = 0; j < NCLS; ++j) m = fmaxf(m, s_log[c * NCLS + j]);
        float den = 0.f;
        for (int j = 1; j < NCLS; ++j) den += expf(s_log[c * NCLS + j] - m);
        s_term[c] = logf(den) - (s_log[c * NCLS + c] - m);
    }
    __syncthreads();

    if (threadIdx.x == 0) {
        float acc = 0.f;
        for (int c = 1; c < NCLS; ++c) acc += s_term[c];
        out[0] = acc / (float)(NCLS - 1);
    }
}

// ---------------------------------------------------------------------------
extern "C" void kernel_launch(void* const* d_in, const int* in_sizes, int n_in,
                              void* d_out, int out_size, void* d_ws, size_t ws_size,
                              hipStream_t stream) {
    const float* feat  = (const float*)d_in[0];
    const float* proto = (const float*)d_in[1];
    const int*   lab   = (const int*)d_in[3];   // d_in[2] "outputs" unused

    const int N = in_sizes[3];                  // 589824 = 256 * 18 * 128

    float* gsum = (float*)d_ws;                 // [8][21*256]
    float* gcnt = gsum + NREP * NCLS * FEAT_DIM;

    hipMemsetAsync(gsum, 0,
                   (NREP * NCLS * FEAT_DIM + NCLS) * sizeof(float), stream);

    k_fused<<<256, 512, 0, stream>>>(feat, lab, gsum, gcnt, N);
    k_final<<<1, 256, 0, stream>>>(gsum, gcnt, proto, (float*)d_out);
}

// Round 11
// 178.721 us; speedup vs baseline: 2.0468x; 2.0468x over previous
//
#include <hip/hip_runtime.h>
#include <math.h>

#define FEAT_DIM 256
#define NCLS 21
#define TEMP 0.1f
#define NREP 8

typedef float f32x4  __attribute__((ext_vector_type(4)));
typedef float f32x16 __attribute__((ext_vector_type(16)));
typedef int   i32x4  __attribute__((ext_vector_type(4)));
typedef unsigned int u32x4 __attribute__((ext_vector_type(4)));
typedef short bf16x8 __attribute__((ext_vector_type(8)));

__device__ __forceinline__ unsigned int cvt_pk_bf16(float lo, float hi) {
    unsigned int r;
    asm("v_cvt_pk_bf16_f32 %0, %1, %2" : "=v"(r) : "v"(lo), "v"(hi));
    return r;
}

template <int CTRL>
__device__ __forceinline__ float dpp_add(float x) {
    int y = __builtin_amdgcn_update_dpp(
        0, __builtin_bit_cast(int, x), CTRL, 0xF, 0xF, true);
    return x + __builtin_bit_cast(float, y);
}
// sum over each 16-lane group: xor1 (quad_perm 1,0,3,2), xor2 (2,3,0,1),
// xor7 (row_half_mirror), xor8 (row_ror:8). VALU-only, no DS traffic.
__device__ __forceinline__ float sum16(float x) {
    x = dpp_add<0xB1>(x);
    x = dpp_add<0x4E>(x);
    x = dpp_add<0x141>(x);
    x = dpp_add<0x128>(x);
    return x;
}

// ---------------------------------------------------------------------------
// MFMA scatter-mean: sums[c][d] = sum_px onehot[c][px] * bf16(f[d][px]*iv[px]).
// Wave w owns channels [32w,32w+32); acc[32cls][32ch] lives in 16 MFMA acc
// regs for the entire kernel -> ZERO per-element LDS flush traffic.
// Per 32-px tile: P1 prefetch(t+1) + ssq DPP-tree partials -> LDS;
// B1; P2 iv (w0) + labels/count (w1); B2; P3 pack B-frags + onehot A + 2 mfma.
// Raw s_barrier + lgkm-only fences keep prefetch loads in flight.
// ---------------------------------------------------------------------------
__global__ __launch_bounds__(512, 2)
void k_fused(const float* __restrict__ feat, const int* __restrict__ lab,
             float* __restrict__ gsum, float* __restrict__ gcnt, int N) {
    __shared__ float s_ssp[8][2][32];   // [wave][ch-group][px] 16-ch partials
    __shared__ float s_ivf[32];
    __shared__ int   s_lab[32];

    const int tid = threadIdx.x, lane = tid & 63, w = tid >> 6;
    const int half = lane >> 5, ch = lane & 31;   // ch = B-col = A-row(class)
    const int ntile = N / (gridDim.x * 32);       // 36
    const size_t px0 = (size_t)blockIdx.x * ntile * 32;

    // element address for tile t, chunk c (0..1), part p (0..1):
    //   fbase + t*32 + c*16 + p*4   (k = half*8 + p*4 + e)
    const float* fbase = feat + (size_t)(w * 32 + ch) * (size_t)N + px0 + half * 8;

    f32x16 acc = 0.0f;
    float cntacc = 0.f;
    float4 VA[4], VB[4];
    int labA = 0, labB = 0;

    // prologue: tile 0
    if (w == 1) labA = lab[px0 + (lane & 31)];
    #pragma unroll
    for (int j = 0; j < 4; ++j)
        VA[j] = *reinterpret_cast<const float4*>(fbase + (j >> 1) * 16 + (j & 1) * 4);

    auto process = [&](int t, float4 (&VC)[4], int labc,
                       float4 (&VN)[4], int& labn) {
        // ---- P1: prefetch t+1 (stays in flight across raw barriers)
        if (t + 1 < ntile) {
            if (w == 1) labn = lab[px0 + (size_t)(t + 1) * 32 + (lane & 31)];
            const float* fn_ = fbase + (size_t)(t + 1) * 32;
            #pragma unroll
            for (int j = 0; j < 4; ++j)
                VN[j] = *reinterpret_cast<const float4*>(fn_ + (j >> 1) * 16 + (j & 1) * 4);
        }
        // ssq partials: DPP tree over 16-lane channel groups
        #pragma unroll
        for (int c = 0; c < 2; ++c) {
            const float4 v0 = VC[2 * c], v1 = VC[2 * c + 1];
            const float s0 = sum16(v0.x * v0.x);
            const float s1 = sum16(v0.y * v0.y);
            const float s2 = sum16(v0.z * v0.z);
            const float s3 = sum16(v0.w * v0.w);
            const float s4 = sum16(v1.x * v1.x);
            const float s5 = sum16(v1.y * v1.y);
            const float s6 = sum16(v1.z * v1.z);
            const float s7 = sum16(v1.w * v1.w);
            if ((lane & 15) == 0) {             // lanes 0,16,32,48
                float* b = &s_ssp[w][(lane >> 4) & 1][c * 16 + half * 8];
                *reinterpret_cast<f32x4*>(b)     = (f32x4){s0, s1, s2, s3};
                *reinterpret_cast<f32x4*>(b + 4) = (f32x4){s4, s5, s6, s7};
            }
        }
        asm volatile("s_waitcnt lgkmcnt(0)" ::: "memory");
        __builtin_amdgcn_s_barrier();                       // B1

        // ---- P2: w0 -> iv; w1 -> labels + counts
        if (w == 0 && lane < 32) {
            float ss = 0.f;
            #pragma unroll
            for (int q = 0; q < 8; ++q)
                ss += s_ssp[q][0][lane] + s_ssp[q][1][lane];
            s_ivf[lane] = 1.0f / fmaxf(sqrtf(ss), 1e-12f);
        }
        if (w == 1) {
            if (lane < 32) s_lab[lane] = labc;
            #pragma unroll 1
            for (int c = 0; c < NCLS; ++c) {
                const unsigned long long m =
                    __ballot(labc == c) & 0xFFFFFFFFull;    // low 32 = true px
                if (lane == c) cntacc += (float)__popcll(m);
            }
        }
        asm volatile("s_waitcnt lgkmcnt(0)" ::: "memory");
        __builtin_amdgcn_s_barrier();                       // B2

        // ---- P3: build fragments, 2 x mfma 32x32x16
        #pragma unroll
        for (int c = 0; c < 2; ++c) {
            const int o = c * 16 + half * 8;
            const i32x4 lb0 = *reinterpret_cast<const i32x4*>(&s_lab[o]);
            const i32x4 lb1 = *reinterpret_cast<const i32x4*>(&s_lab[o + 4]);
            const f32x4 iv0 = *reinterpret_cast<const f32x4*>(&s_ivf[o]);
            const f32x4 iv1 = *reinterpret_cast<const f32x4*>(&s_ivf[o + 4]);
            const float4 v0 = VC[2 * c], v1 = VC[2 * c + 1];
            u32x4 bw, aw;
            bw[0] = cvt_pk_bf16(v0.x * iv0[0], v0.y * iv0[1]);
            bw[1] = cvt_pk_bf16(v0.z * iv0[2], v0.w * iv0[3]);
            bw[2] = cvt_pk_bf16(v1.x * iv1[0], v1.y * iv1[1]);
            bw[3] = cvt_pk_bf16(v1.z * iv1[2], v1.w * iv1[3]);
            aw[0] = (lb0[0] == ch ? 0x3F80u : 0u) | (lb0[1] == ch ? 0x3F800000u : 0u);
            aw[1] = (lb0[2] == ch ? 0x3F80u : 0u) | (lb0[3] == ch ? 0x3F800000u : 0u);
            aw[2] = (lb1[0] == ch ? 0x3F80u : 0u) | (lb1[1] == ch ? 0x3F800000u : 0u);
            aw[3] = (lb1[2] == ch ? 0x3F80u : 0u) | (lb1[3] == ch ? 0x3F800000u : 0u);
            acc = __builtin_amdgcn_mfma_f32_32x32x16_bf16(
                __builtin_bit_cast(bf16x8, aw),
                __builtin_bit_cast(bf16x8, bw), acc, 0, 0, 0);
        }
    };

    for (int t = 0; t < ntile; t += 2) {      // 36 tiles, even
        process(t,     VA, labA, VB, labB);
        process(t + 1, VB, labB, VA, labA);
    }

    // ---- merge: acc -> global replica (one atomic per cell per block)
    {
        float* grep = gsum + (size_t)(blockIdx.x & (NREP - 1)) * (NCLS * FEAT_DIM);
        const int dcol = w * 32 + ch;
        #pragma unroll
        for (int r = 0; r < 16; ++r) {
            const int row = (r & 3) + 8 * (r >> 2) + 4 * half;   // class
            if (row < NCLS) atomicAdd(&grep[row * FEAT_DIM + dcol], acc[r]);
        }
    }
    if (w == 1 && lane < NCLS) atomicAdd(&gcnt[lane], cntacc);
}

// ---------------------------------------------------------------------------
// Finalize: sum replicas -> means -> 21x21 logits -> masked loss.
// ---------------------------------------------------------------------------
__global__ void k_final(const float* __restrict__ gsum,
                        const float* __restrict__ gcnt,
                        const float* __restrict__ proto,
                        float* __restrict__ out) {
    __shared__ float s_mean[NCLS * 257];
    __shared__ float s_icnt[NCLS];
    __shared__ float s_log[NCLS * NCLS];
    __shared__ float s_term[NCLS];

    if (threadIdx.x < NCLS)
        s_icnt[threadIdx.x] = 1.0f / fmaxf(gcnt[threadIdx.x], 1.0f);
    __syncthreads();

    for (int i = threadIdx.x; i < NCLS * FEAT_DIM; i += blockDim.x) {
        float v = 0.f;
        #pragma unroll
        for (int r = 0; r < NREP; ++r) v += gsum[r * NCLS * FEAT_DIM + i];
        const int c = i / FEAT_DIM, d = i - c * FEAT_DIM;
        s_mean[c * 257 + d] = v * s_icnt[c];
    }
    __syncthreads();

    for (int p = threadIdx.x; p < NCLS * NCLS; p += blockDim.x) {
        const int c = p / NCLS, j = p - c * NCLS;
        float acc = 0.f;
        #pragma unroll 8
        for (int d = 0; d < FEAT_DIM; ++d)
            acc += s_mean[c * 257 + d] * proto[j * FEAT_DIM + d];
        s_log[p] = acc / TEMP;
    }
    __syncthreads();

    if (threadIdx.x >= 1 && threadIdx.x < NCLS) {
        const int c = threadIdx.x;
        float m = -INFINITY;
        for (int j = 0; j < NCLS; ++j) m = fmaxf(m, s_log[c * NCLS + j]);
        float den = 0.f;
        for (int j = 1; j < NCLS; ++j) den += expf(s_log[c * NCLS + j] - m);
        s_term[c] = logf(den) - (s_log[c * NCLS + c] - m);
    }
    __syncthreads();

    if (threadIdx.x == 0) {
        float acc = 0.f;
        for (int c = 1; c < NCLS; ++c) acc += s_term[c];
        out[0] = acc / (float)(NCLS - 1);
    }
}

// ---------------------------------------------------------------------------
extern "C" void kernel_launch(void* const* d_in, const int* in_sizes, int n_in,
                              void* d_out, int out_size, void* d_ws, size_t ws_size,
                              hipStream_t stream) {
    const float* feat  = (const float*)d_in[0];
    const float* proto = (const float*)d_in[1];
    const int*   lab   = (const int*)d_in[3];   // d_in[2] "outputs" unused

    const int N = in_sizes[3];                  // 589824 = 512 * 36 * 32

    float* gsum = (float*)d_ws;                 // [NREP][21*256]
    float* gcnt = gsum + NREP * NCLS * FEAT_DIM;

    (void)hipMemsetAsync(gsum, 0,
                         (NREP * NCLS * FEAT_DIM + NCLS) * sizeof(float), stream);

    k_fused<<<512, 512, 0, stream>>>(feat, lab, gsum, gcnt, N);
    k_final<<<1, 256, 0, stream>>>(gsum, gcnt, proto, (float*)d_out);
}

// Round 12
// 166.417 us; speedup vs baseline: 2.1982x; 1.0739x over previous
//
#include <hip/hip_runtime.h>
#include <math.h>

#define FEAT_DIM 256
#define NCLS 21
#define TEMP 0.1f
#define NREP 8

typedef float f32x4  __attribute__((ext_vector_type(4)));
typedef float f32x16 __attribute__((ext_vector_type(16)));
typedef int   i32x4  __attribute__((ext_vector_type(4)));
typedef unsigned int u32x4 __attribute__((ext_vector_type(4)));
typedef short bf16x8 __attribute__((ext_vector_type(8)));

__device__ __forceinline__ unsigned int cvt_pk_bf16(float lo, float hi) {
    unsigned int r;
    asm("v_cvt_pk_bf16_f32 %0, %1, %2" : "=v"(r) : "v"(lo), "v"(hi));
    return r;
}

template <int CTRL>
__device__ __forceinline__ float dpp_add(float x) {
    int y = __builtin_amdgcn_update_dpp(
        0, __builtin_bit_cast(int, x), CTRL, 0xF, 0xF, true);
    return x + __builtin_bit_cast(float, y);
}
// sum over each 16-lane group (VALU-only, no DS traffic)
__device__ __forceinline__ float sum16(float x) {
    x = dpp_add<0xB1>(x);    // quad_perm xor1
    x = dpp_add<0x4E>(x);    // quad_perm xor2
    x = dpp_add<0x141>(x);   // row_half_mirror (xor4)
    x = dpp_add<0x128>(x);   // row_ror:8 (xor8 within 16)
    return x;
}

// ---------------------------------------------------------------------------
// MFMA scatter-mean with DEPTH-2 prefetch (triple buffer).
// sums[c][d] = sum_px onehot[c][px] * bf16(f[d][px]*iv[px]).
// Wave w owns channels [32w,32w+32); acc[32cls][32ch] = 16 MFMA acc regs for
// the whole kernel (zero per-element LDS flush). Per 32-px tile:
//   P1: issue loads for tile t+2 (dep distance ~2 bodies > 900cy HBM miss
//       latency -> no steady-state stall) + ssq DPP partials -> LDS
//   B1; P2: w0 iv, w1 labels (ballot-count moved OUT of this phase); B2;
//   P3: pack B-frags + onehot A + 2 mfma; w1 ballot-counts here, overlapped.
// Raw s_barrier + lgkm-only fences keep prefetch loads in flight.
// ---------------------------------------------------------------------------
__global__ __launch_bounds__(512, 2)
void k_fused(const float* __restrict__ feat, const int* __restrict__ lab,
             float* __restrict__ gsum, float* __restrict__ gcnt, int N) {
    __shared__ float s_ssp[8][2][32];   // [wave][ch-group][px] 16-ch partials
    __shared__ float s_ivf[32];
    __shared__ int   s_lab[32];

    const int tid = threadIdx.x, lane = tid & 63, w = tid >> 6;
    const int half = lane >> 5, ch = lane & 31;   // ch = B-col = A-row(class)
    const int ntile = N / (gridDim.x * 32);       // 36
    const size_t px0 = (size_t)blockIdx.x * ntile * 32;

    const float* fbase = feat + (size_t)(w * 32 + ch) * (size_t)N + px0 + half * 8;

    f32x16 acc = 0.0f;
    float cntacc = 0.f;
    float4 VA[4], VB[4], VC3[4];
    int labA = 0, labB = 0, labC = 0;

    // prologue: tiles 0 and 1 in flight
    if (w == 1) labA = lab[px0 + (lane & 31)];
    #pragma unroll
    for (int j = 0; j < 4; ++j)
        VA[j] = *reinterpret_cast<const float4*>(fbase + (j >> 1) * 16 + (j & 1) * 4);
    if (w == 1) labB = lab[px0 + 32 + (lane & 31)];
    #pragma unroll
    for (int j = 0; j < 4; ++j)
        VB[j] = *reinterpret_cast<const float4*>(fbase + 32 + (j >> 1) * 16 + (j & 1) * 4);

    auto process = [&](int t, float4 (&VC)[4], int labc,
                       float4 (&VN2)[4], int& labn2) {
        // ---- P1: issue tile t+2 loads (stay in flight across raw barriers)
        if (t + 2 < ntile) {
            if (w == 1) labn2 = lab[px0 + (size_t)(t + 2) * 32 + (lane & 31)];
            const float* fn_ = fbase + (size_t)(t + 2) * 32;
            #pragma unroll
            for (int j = 0; j < 4; ++j)
                VN2[j] = *reinterpret_cast<const float4*>(fn_ + (j >> 1) * 16 + (j & 1) * 4);
        }
        // ssq partials: DPP tree over 16-lane channel groups
        #pragma unroll
        for (int c = 0; c < 2; ++c) {
            const float4 v0 = VC[2 * c], v1 = VC[2 * c + 1];
            const float s0 = sum16(v0.x * v0.x);
            const float s1 = sum16(v0.y * v0.y);
            const float s2 = sum16(v0.z * v0.z);
            const float s3 = sum16(v0.w * v0.w);
            const float s4 = sum16(v1.x * v1.x);
            const float s5 = sum16(v1.y * v1.y);
            const float s6 = sum16(v1.z * v1.z);
            const float s7 = sum16(v1.w * v1.w);
            if ((lane & 15) == 0) {             // lanes 0,16,32,48
                float* b = &s_ssp[w][(lane >> 4) & 1][c * 16 + half * 8];
                *reinterpret_cast<f32x4*>(b)     = (f32x4){s0, s1, s2, s3};
                *reinterpret_cast<f32x4*>(b + 4) = (f32x4){s4, s5, s6, s7};
            }
        }
        asm volatile("s_waitcnt lgkmcnt(0)" ::: "memory");
        __builtin_amdgcn_s_barrier();                       // B1

        // ---- P2 (kept minimal): w0 -> iv; w1 -> publish labels
        if (w == 0 && lane < 32) {
            float ss = 0.f;
            #pragma unroll
            for (int q = 0; q < 8; ++q)
                ss += s_ssp[q][0][lane] + s_ssp[q][1][lane];
            s_ivf[lane] = 1.0f / fmaxf(sqrtf(ss), 1e-12f);
        }
        if (w == 1 && lane < 32) s_lab[lane] = labc;
        asm volatile("s_waitcnt lgkmcnt(0)" ::: "memory");
        __builtin_amdgcn_s_barrier();                       // B2

        // ---- P3: build fragments, 2 x mfma 32x32x16
        #pragma unroll
        for (int c = 0; c < 2; ++c) {
            const int o = c * 16 + half * 8;
            const i32x4 lb0 = *reinterpret_cast<const i32x4*>(&s_lab[o]);
            const i32x4 lb1 = *reinterpret_cast<const i32x4*>(&s_lab[o + 4]);
            const f32x4 iv0 = *reinterpret_cast<const f32x4*>(&s_ivf[o]);
            const f32x4 iv1 = *reinterpret_cast<const f32x4*>(&s_ivf[o + 4]);
            const float4 v0 = VC[2 * c], v1 = VC[2 * c + 1];
            u32x4 bw, aw;
            bw[0] = cvt_pk_bf16(v0.x * iv0[0], v0.y * iv0[1]);
            bw[1] = cvt_pk_bf16(v0.z * iv0[2], v0.w * iv0[3]);
            bw[2] = cvt_pk_bf16(v1.x * iv1[0], v1.y * iv1[1]);
            bw[3] = cvt_pk_bf16(v1.z * iv1[2], v1.w * iv1[3]);
            aw[0] = (lb0[0] == ch ? 0x3F80u : 0u) | (lb0[1] == ch ? 0x3F800000u : 0u);
            aw[1] = (lb0[2] == ch ? 0x3F80u : 0u) | (lb0[3] == ch ? 0x3F800000u : 0u);
            aw[2] = (lb1[0] == ch ? 0x3F80u : 0u) | (lb1[1] == ch ? 0x3F800000u : 0u);
            aw[3] = (lb1[2] == ch ? 0x3F80u : 0u) | (lb1[3] == ch ? 0x3F800000u : 0u);
            acc = __builtin_amdgcn_mfma_f32_32x32x16_bf16(
                __builtin_bit_cast(bf16x8, aw),
                __builtin_bit_cast(bf16x8, bw), acc, 0, 0, 0);
        }

        // ---- w1 counts here (overlaps other waves' P3/P1; no barrier waits)
        if (w == 1) {
            #pragma unroll 1
            for (int c = 0; c < NCLS; ++c) {
                const unsigned long long m =
                    __ballot(labc == c) & 0xFFFFFFFFull;    // low 32 = real px
                if (lane == c) cntacc += (float)__popcll(m);
            }
        }
    };

    for (int t = 0; t < ntile; t += 3) {      // 36 % 3 == 0
        process(t,     VA,  labA, VC3, labC);
        process(t + 1, VB,  labB, VA,  labA);
        process(t + 2, VC3, labC, VB,  labB);
    }

    // ---- merge: acc -> global replica (one atomic per cell per block)
    {
        float* grep = gsum + (size_t)(blockIdx.x & (NREP - 1)) * (NCLS * FEAT_DIM);
        const int dcol = w * 32 + ch;
        #pragma unroll
        for (int r = 0; r < 16; ++r) {
            const int row = (r & 3) + 8 * (r >> 2) + 4 * half;   // class
            if (row < NCLS) atomicAdd(&grep[row * FEAT_DIM + dcol], acc[r]);
        }
    }
    if (w == 1 && lane < NCLS) atomicAdd(&gcnt[lane], cntacc);
}

// ---------------------------------------------------------------------------
// Finalize: sum replicas -> means -> 21x21 logits -> masked loss.
// ---------------------------------------------------------------------------
__global__ void k_final(const float* __restrict__ gsum,
                        const float* __restrict__ gcnt,
                        const float* __restrict__ proto,
                        float* __restrict__ out) {
    __shared__ float s_mean[NCLS * 257];
    __shared__ float s_icnt[NCLS];
    __shared__ float s_log[NCLS * NCLS];
    __shared__ float s_term[NCLS];

    if (threadIdx.x < NCLS)
        s_icnt[threadIdx.x] = 1.0f / fmaxf(gcnt[threadIdx.x], 1.0f);
    __syncthreads();

    for (int i = threadIdx.x; i < NCLS * FEAT_DIM; i += blockDim.x) {
        float v = 0.f;
        #pragma unroll
        for (int r = 0; r < NREP; ++r) v += gsum[r * NCLS * FEAT_DIM + i];
        const int c = i / FEAT_DIM, d = i - c * FEAT_DIM;
        s_mean[c * 257 + d] = v * s_icnt[c];
    }
    __syncthreads();

    for (int p = threadIdx.x; p < NCLS * NCLS; p += blockDim.x) {
        const int c = p / NCLS, j = p - c * NCLS;
        float acc = 0.f;
        #pragma unroll 8
        for (int d = 0; d < FEAT_DIM; ++d)
            acc += s_mean[c * 257 + d] * proto[j * FEAT_DIM + d];
        s_log[p] = acc / TEMP;
    }
    __syncthreads();

    if (threadIdx.x >= 1 && threadIdx.x < NCLS) {
        const int c = threadIdx.x;
        float m = -INFINITY;
        for (int j = 0; j < NCLS; ++j) m = fmaxf(m, s_log[c * NCLS + j]);
        float den = 0.f;
        for (int j = 1; j < NCLS; ++j) den += expf(s_log[c * NCLS + j] - m);
        s_term[c] = logf(den) - (s_log[c * NCLS + c] - m);
    }
    __syncthreads();

    if (threadIdx.x == 0) {
        float acc = 0.f;
        for (int c = 1; c < NCLS; ++c) acc += s_term[c];
        out[0] = acc / (float)(NCLS - 1);
    }
}

// ---------------------------------------------------------------------------
extern "C" void kernel_launch(void* const* d_in, const int* in_sizes, int n_in,
                              void* d_out, int out_size, void* d_ws, size_t ws_size,
                              hipStream_t stream) {
    const float* feat  = (const float*)d_in[0];
    const float* proto = (const float*)d_in[1];
    const int*   lab   = (const int*)d_in[3];   // d_in[2] "outputs" unused

    const int N = in_sizes[3];                  // 589824 = 512 * 36 * 32

    float* gsum = (float*)d_ws;                 // [NREP][21*256]
    float* gcnt = gsum + NREP * NCLS * FEAT_DIM;

    (void)hipMemsetAsync(gsum, 0,
                         (NREP * NCLS * FEAT_DIM + NCLS) * sizeof(float), stream);

    k_fused<<<512, 512, 0, stream>>>(feat, lab, gsum, gcnt, N);
    k_final<<<1, 256, 0, stream>>>(gsum, gcnt, proto, (float*)d_out);
}